// Round 13
// baseline (467.285 us; speedup 1.0000x reference)
//
#include <hip/hip_runtime.h>
#include <hip/hip_bf16.h>

// Problem constants
#define NN 240        // rows (tokens)
#define CC 6144       // channels
#define DD 3072       // head dim
#define C3 18432      // 3*C
#define HH 2          // heads

typedef __attribute__((ext_vector_type(8))) short bf16x8;
typedef __attribute__((ext_vector_type(4))) float f32x4;
typedef unsigned short ushort_t;

static __device__ __forceinline__ unsigned short f2bf(float f) {
    __hip_bfloat16 h = __float2bfloat16(f);
    return __builtin_bit_cast(unsigned short, h);
}

// global -> LDS direct DMA, 16 B per lane, LDS dest wave-uniform base.
#define GLDS16(g, l) __builtin_amdgcn_global_load_lds( \
    (const __attribute__((address_space(1))) void*)(g), \
    (__attribute__((address_space(3))) void*)(l), 16, 0, 0)

// ---------------------------------------------------------------------------
// gemm_pc ("producer-consumer"): C[240 x N] = A_bf16[256xK] * B_fp32[NxK]^T.
// 320 threads = 4 compute waves + 1 producer wave. vmcnt is PER-WAVE, so
// giving B its own wave gives B a private FIFO: producer's vmcnt(0) drain
// overlaps consumer compute completely (the R2-R12 failure was A-waits and
// B-waits sharing one FIFO -> every A-wait forced B drained).
//   producer: stages B tile [64 cols x 128 k] fp32 into dbuf LDS via 32
//     GLDS of 512-B column bursts (DRAM row locality), vmcnt(0), then the
//     single per-tile barrier. B cover = a whole tile of consumer compute.
//   consumers: wave-private A staging (R11 loader, wave's own 64 rows ->
//     NO barriers for A); per 32-k inner step: 4 GLDS -> vmcnt(0) (A-only
//     FIFO, L2-fast) -> frag reads -> lgkmcnt(0)+sched_barrier -> 16 MFMA.
// Barriers: exactly 1 per 128-k outer tile (+1 prologue), both roles.
// LDS: A 4x4 KB wave-private + B 2x32 KB = 80 KB -> 2 blocks/CU.
// ---------------------------------------------------------------------------
__global__ __launch_bounds__(320, 2)
void gemm_pc(const ushort_t* __restrict__ Ab, int lda,
             const float* __restrict__ B, int ldb,
             const float* __restrict__ bias,
             float* __restrict__ C0,
             float* __restrict__ CP, long long sCPz,
             int ldc, int N, int Kc, int KS,
             ushort_t* __restrict__ Qb) {
    __shared__ ushort_t sA[4][64 * 32];   // 16 KB (wave-private 4 KB blocks)
    __shared__ float    sB[2][64 * 128];  // 64 KB

    const int kc = blockIdx.z;
    const ushort_t* Abase = Ab + (size_t)kc * Kc;
    const float*    Bbase = B  + (size_t)kc * Kc;
    float* Cw = (kc == 0) ? C0 : (CP + (size_t)(kc - 1) * sCPz);

    const int n0 = blockIdx.x * 64;
    const int tid = threadIdx.x, lane = tid & 63, wid = tid >> 6; // 0..4
    const int l16 = lane & 15, lk = lane >> 4;
    const int nT = Kc / 128;              // outer tiles
    const bool producer = (wid == 4);

    // producer addressing: instr i covers cols 2i,2i+1 (512 B each).
    // Lane l -> col 2i+(l>>5), 16B-slot l&31 <- source slot (l&31)^(col&7)
    // (involution; read XORs the same).
    const int chalf = lane >> 5;
    const int sl = lane & 31;

    // consumer A addressing (R11-proven, wave-private rows wid*64..+63):
    // instr i covers local rows i*16..+15; lane l -> row +(l>>2),
    // phys slot l&3 <- source k-oct (l&3)^((l>>3)&3).
    const int ar = lane >> 2;
    const int akoct = (lane & 3) ^ ((lane >> 3) & 3);

    f32x4 acc[4][4] = {};

    // Prologue: producer stages B(0); everyone hits barrier #0.
    if (producer) {
#pragma unroll
        for (int i = 0; i < 32; ++i) {
            int col = 2 * i + chalf;
            const float* src = Bbase + (size_t)(n0 + col) * ldb
                               + ((sl ^ (col & 7)) * 4);
            GLDS16(src, &sB[0][i * 256]);
        }
        asm volatile("s_waitcnt vmcnt(0)" ::: "memory");
    }
    __syncthreads();

    for (int T = 0; T < nT; ++T) {
        if (producer) {
            if (T + 1 < nT) {
#pragma unroll
                for (int i = 0; i < 32; ++i) {
                    int col = 2 * i + chalf;
                    const float* src = Bbase + (size_t)(n0 + col) * ldb
                                       + (size_t)(T + 1) * 128
                                       + ((sl ^ (col & 7)) * 4);
                    GLDS16(src, &sB[(T + 1) & 1][i * 256]);
                }
                asm volatile("s_waitcnt vmcnt(0)" ::: "memory");
            }
        } else {
            const float* Bs = sB[T & 1];
#pragma unroll
            for (int s = 0; s < 4; ++s) {
                // stage own A rows for k-slice T*4+s (wave-private)
#pragma unroll
                for (int i = 0; i < 4; ++i) {
                    GLDS16(Abase + (size_t)(wid * 64 + i * 16 + ar) * lda
                               + akoct * 8 + (size_t)(T * 4 + s) * 32,
                           &sA[wid][i * 512]);
                }
                asm volatile("s_waitcnt vmcnt(0)" ::: "memory");
                __builtin_amdgcn_sched_barrier(0);

                bf16x8 af[4];
#pragma unroll
                for (int mt = 0; mt < 4; ++mt) {
                    int lr = mt * 16 + l16;
                    af[mt] = *(const bf16x8*)((const char*)sA[wid] + lr * 64
                                + ((lk ^ ((lr >> 1) & 3)) * 16));
                }
#pragma unroll
                for (int nf = 0; nf < 4; ++nf) {
                    int c = nf * 16 + l16;
                    int j0 = (s * 8 + 2 * lk) ^ (c & 7);
                    int j1 = (s * 8 + 2 * lk + 1) ^ (c & 7);
                    const char* cb = (const char*)(Bs + c * 128);
                    f32x4 lo = *(const f32x4*)(cb + j0 * 16);
                    f32x4 hi = *(const f32x4*)(cb + j1 * 16);
                    bf16x8 r;
                    r[0] = (short)f2bf(lo[0]); r[1] = (short)f2bf(lo[1]);
                    r[2] = (short)f2bf(lo[2]); r[3] = (short)f2bf(lo[3]);
                    r[4] = (short)f2bf(hi[0]); r[5] = (short)f2bf(hi[1]);
                    r[6] = (short)f2bf(hi[2]); r[7] = (short)f2bf(hi[3]);
#pragma unroll
                    for (int mt = 0; mt < 4; ++mt)
                        acc[mt][nf] = __builtin_amdgcn_mfma_f32_16x16x32_bf16(
                            af[mt], r, acc[mt][nf], 0, 0, 0);
                }
                // all LDS reads of this step done before next step's DMA
                asm volatile("s_waitcnt lgkmcnt(0)" ::: "memory");
                __builtin_amdgcn_sched_barrier(0);
            }
        }
        __syncthreads();   // tile fence: B(T+1) ready / sB[T&1] reusable
    }

    // Epilogue (consumers only): fragment row = lk*4+j, col = nf*16+l16
    if (!producer) {
#pragma unroll
        for (int mt = 0; mt < 4; ++mt) {
#pragma unroll
            for (int j = 0; j < 4; ++j) {
                int grow = wid * 64 + mt * 16 + lk * 4 + j;
                if (grow < NN) {
#pragma unroll
                    for (int nf = 0; nf < 4; ++nf) {
                        int gcol = n0 + nf * 16 + l16;
                        if (gcol < N) {
                            float v = acc[mt][nf][j];
                            if (kc == 0 && bias) v += bias[gcol];
                            Cw[(size_t)grow * ldc + gcol] = v;
                            if (Qb && gcol < CC)
                                Qb[(size_t)grow * CC + gcol] = f2bf(v);
                        }
                    }
                }
            }
        }
    }
}

// ---------------------------------------------------------------------------
// gemm_m97 (R11/R12, proven): used for QK^T (small, L2-resident operands).
// ---------------------------------------------------------------------------
__global__ __launch_bounds__(256, 4)
void gemm_m97(const ushort_t* __restrict__ Ab, int lda, long long sAz,
              const float* __restrict__ B, int ldb, long long sBz,
              float* __restrict__ C0, long long sC0z,
              float* __restrict__ CP, long long sCPz,
              int ldc, int N, int Kc, int KS) {
    __shared__ ushort_t sA[256 * 32];   // 16 KB
    __shared__ float    sB[64 * 32];    //  8 KB

    const int zc = blockIdx.z;
    const int z = zc / KS, kc = zc % KS;
    const ushort_t* Abase = Ab + (size_t)z * sAz + (size_t)kc * Kc;
    const float*    Bbase = B  + (size_t)z * sBz + (size_t)kc * Kc;
    float* Cw = (kc == 0) ? (C0 + (size_t)z * sC0z)
                          : (CP + (size_t)(z * (KS - 1) + kc - 1) * sCPz);

    const int n0 = blockIdx.x * 64;
    const int tid = threadIdx.x, lane = tid & 63, wid = tid >> 6;
    const int l16 = lane & 15, lk = lane >> 4;

    const int ar = lane >> 2;
    const int akoct = (lane & 3) ^ ((lane >> 3) & 3);

    long long bofs[2];
#pragma unroll
    for (int i = 0; i < 2; ++i) {
        int cl = (wid * 2 + i) * 8 + (lane >> 3);
        int cg = n0 + cl; if (cg > N - 1) cg = N - 1;
        bofs[i] = (long long)cg * ldb + ((lane & 7) ^ ((lane >> 3) & 7)) * 4;
    }

    const int nt = Kc / 32;
    f32x4 acc[4][4] = {};

    for (int t = 0; t < nt; ++t) {
#pragma unroll
        for (int i = 0; i < 4; ++i) {
            int rb = (wid * 4 + i) * 16;
            GLDS16(Abase + (size_t)(rb + ar) * lda + akoct * 8 + (size_t)t * 32,
                   sA + rb * 32);
        }
#pragma unroll
        for (int i = 0; i < 2; ++i) {
            int cb = (wid * 2 + i) * 8;
            GLDS16(Bbase + bofs[i] + (size_t)t * 32, sB + cb * 32);
        }
        __syncthreads();

        bf16x8 af[4];
#pragma unroll
        for (int mt = 0; mt < 4; ++mt) {
            int r = wid * 64 + mt * 16 + l16;
            af[mt] = *(const bf16x8*)((const char*)sA + r * 64
                        + ((lk ^ ((r >> 1) & 3)) * 16));
        }
#pragma unroll
        for (int nf = 0; nf < 4; ++nf) {
            int c = nf * 16 + l16;
            const char* cb = (const char*)sB + c * 128;
            f32x4 lo = *(const f32x4*)(cb + (((2 * lk) ^ (c & 7)) * 16));
            f32x4 hi = *(const f32x4*)(cb + (((2 * lk + 1) ^ (c & 7)) * 16));
            bf16x8 r;
            r[0] = (short)f2bf(lo[0]); r[1] = (short)f2bf(lo[1]);
            r[2] = (short)f2bf(lo[2]); r[3] = (short)f2bf(lo[3]);
            r[4] = (short)f2bf(hi[0]); r[5] = (short)f2bf(hi[1]);
            r[6] = (short)f2bf(hi[2]); r[7] = (short)f2bf(hi[3]);
#pragma unroll
            for (int mt = 0; mt < 4; ++mt)
                acc[mt][nf] = __builtin_amdgcn_mfma_f32_16x16x32_bf16(
                    af[mt], r, acc[mt][nf], 0, 0, 0);
        }
        __syncthreads();
    }

#pragma unroll
    for (int mt = 0; mt < 4; ++mt) {
#pragma unroll
        for (int j = 0; j < 4; ++j) {
            int grow = wid * 64 + mt * 16 + lk * 4 + j;
            if (grow < NN) {
#pragma unroll
                for (int nf = 0; nf < 4; ++nf) {
                    int gcol = n0 + nf * 16 + l16;
                    if (gcol < N)
                        Cw[(size_t)grow * ldc + gcol] = acc[mt][nf][j];
                }
            }
        }
    }
}

// xb = bf16(x), rows 240..255 zeroed.
__global__ __launch_bounds__(256)
void convert_kernel(const float* __restrict__ x, ushort_t* __restrict__ xb) {
    int id = blockIdx.x * 256 + threadIdx.x;      // 196608 = 256*6144/8
    int row = id / 768, c8 = id % 768;
    bf16x8 o = {};
    if (row < NN) {
        const float* p = x + (size_t)row * CC + c8 * 8;
        float4 a = *(const float4*)p, b = *(const float4*)(p + 4);
        o[0] = (short)f2bf(a.x); o[1] = (short)f2bf(a.y);
        o[2] = (short)f2bf(a.z); o[3] = (short)f2bf(a.w);
        o[4] = (short)f2bf(b.x); o[5] = (short)f2bf(b.y);
        o[6] = (short)f2bf(b.z); o[7] = (short)f2bf(b.w);
    }
    *(bf16x8*)(xb + (size_t)row * CC + c8 * 8) = o;
}

// out += 3 partials (proj KS=4; bias added by kc==0 epilogue)
__global__ __launch_bounds__(256)
void reduce_proj(float4* __restrict__ o4, const float4* __restrict__ p4,
                 long long s4) {
    int i = blockIdx.x * 256 + threadIdx.x;    // 368,640 float4s
    float4 a = o4[i];
#pragma unroll
    for (int k = 0; k < 3; ++k) {
        float4 b = p4[(size_t)k * s4 + i];
        a.x += b.x; a.y += b.y; a.z += b.z; a.w += b.w;
    }
    o4[i] = a;
}

// qmax[(h*240+n)*12 + c] = max over q[h][n][c*256 .. c*256+255]
__global__ __launch_bounds__(256)
void qmax_kernel(const float* __restrict__ qkv, float* __restrict__ qmax) {
    int idx = blockIdx.x * 4 + (threadIdx.x >> 6);   // 0..5759
    int lane = threadIdx.x & 63;
    int c = idx % 12;
    int r = idx / 12;            // h*240 + n
    int n = r % NN, h = r / NN;
    const float* p = qkv + (size_t)n * C3 + h * DD + c * 256 + lane * 4;
    float4 f = *(const float4*)p;
    float m = fmaxf(fmaxf(f.x, f.y), fmaxf(f.z, f.w));
#pragma unroll
    for (int off = 32; off >= 1; off >>= 1)
        m = fmaxf(m, __shfl_xor(m, off));
    if (lane == 0) qmax[idx] = m;
}

// Softmax rows of (scale * (attn + sum partials) + 0.1*Pq), in place.
__global__ __launch_bounds__(256)
void softmax_kernel(float* __restrict__ attn, const float* __restrict__ gpart,
                    int ksm1, const float* __restrict__ qmax) {
    int r = blockIdx.x * 4 + (threadIdx.x >> 6);   // 0..479 = z*240+n
    int lane = threadIdx.x & 63;
    int z = r / NN, n = r % NN;
    float* row = attn + (size_t)r * NN;
    const float* qm = qmax + r * 12;
    const float scale = 0.0180421959f;             // 3072^-0.5
    float v[4];
    float mx = -1e30f;
#pragma unroll
    for (int i = 0; i < 4; ++i) {
        int m = lane + 64 * i;
        v[i] = -1e30f;
        if (m < NN) {
            float s = row[m];
            for (int kc = 0; kc < ksm1; ++kc)
                s += gpart[(size_t)(z * ksm1 + kc) * (NN * NN)
                           + (size_t)n * NN + m];
            v[i] = s * scale + 0.1f * qm[m % 12];
        }
        mx = fmaxf(mx, v[i]);
    }
#pragma unroll
    for (int off = 32; off >= 1; off >>= 1)
        mx = fmaxf(mx, __shfl_xor(mx, off));
    float s = 0.f;
#pragma unroll
    for (int i = 0; i < 4; ++i) {
        v[i] = __expf(v[i] - mx);
        s += v[i];
    }
#pragma unroll
    for (int off = 32; off >= 1; off >>= 1)
        s += __shfl_xor(s, off);
    float inv = 1.0f / s;
#pragma unroll
    for (int i = 0; i < 4; ++i) {
        int m = lane + 64 * i;
        if (m < NN) row[m] = v[i] * inv;
    }
}

// preb[n][h*3072+dd] = bf16( sum_m attn[h][n][m] * v[h][m][dd] )
__global__ __launch_bounds__(256)
void pv_kernel(const float* __restrict__ attn, const float* __restrict__ qkv,
               ushort_t* __restrict__ preb) {
    const int h = blockIdx.z;
    const int n0 = blockIdx.y * 16;
    const int dd0 = blockIdx.x * 256;
    __shared__ float s_attn[16 * NN];
    for (int i = threadIdx.x; i < 16 * NN; i += 256)
        s_attn[i] = attn[(size_t)h * NN * NN + (n0 + i / NN) * NN + (i % NN)];
    __syncthreads();

    const float* vp = qkv + 2 * CC + h * DD + dd0 + threadIdx.x;
    float acc[16] = {};
    for (int m = 0; m < NN; m += 4) {
        float v0 = vp[(size_t)(m + 0) * C3];
        float v1 = vp[(size_t)(m + 1) * C3];
        float v2 = vp[(size_t)(m + 2) * C3];
        float v3 = vp[(size_t)(m + 3) * C3];
#pragma unroll
        for (int i = 0; i < 16; ++i) {
            float4 a = *(const float4*)&s_attn[i * NN + m];
            acc[i] += a.x * v0 + a.y * v1 + a.z * v2 + a.w * v3;
        }
    }
#pragma unroll
    for (int i = 0; i < 16; ++i)
        preb[(size_t)(n0 + i) * CC + h * DD + dd0 + threadIdx.x] =
            f2bf(acc[i]);
}

extern "C" void kernel_launch(void* const* d_in, const int* in_sizes, int n_in,
                              void* d_out, int out_size, void* d_ws, size_t ws_size,
                              hipStream_t stream) {
    const float* x      = (const float*)d_in[0];
    const float* w_qkv  = (const float*)d_in[1];
    const float* w_proj = (const float*)d_in[2];
    const float* b_proj = (const float*)d_in[3];
    float* out = (float*)d_out;

    // ws layout (floats): qkv 4.42M | attn 115K | qmax 5.8K |
    // xb,qb,preb (bf16 256x6144 each) | gpart 10.4M  => ~70 MB
    const size_t f_qkv  = (size_t)NN * C3;       // 4,423,680
    const size_t f_attn = (size_t)HH * NN * NN;
    const size_t f_qmax = (size_t)HH * NN * 12;
    const size_t f_pre  = (size_t)NN * CC;       // 1,474,560
    float* qkv   = (float*)d_ws;
    float* attn  = qkv + f_qkv;
    float* qmaxb = attn + f_attn;
    ushort_t* xb   = (ushort_t*)(qmaxb + f_qmax);
    ushort_t* qb   = xb + (size_t)256 * CC;
    ushort_t* preb = qb + (size_t)256 * CC;
    float* gpart = (float*)(preb + (size_t)256 * CC);

    // 0. bf16 conversion of x (zero-padded to 256 rows)
    convert_kernel<<<768, 256, 0, stream>>>(x, xb);

    // 1. qkv = x @ w_qkv^T  (KS=1, 288 blocks, all co-resident; emits bf16 Q)
    gemm_pc<<<dim3(C3 / 64, 1, 1), 320, 0, stream>>>(
        xb, CC, w_qkv, CC, nullptr,
        qkv, nullptr, 0LL,
        C3, C3, CC, 1, qb);

    // 2. Pq maxpool over q
    qmax_kernel<<<1440, 256, 0, stream>>>(qkv, qmaxb);

    // 3. attn_raw = Q @ K^T per head (KS=24, 192 blocks, Kc=128, nt=4)
    gemm_m97<<<dim3(4, 1, HH * 24), 256, 0, stream>>>(
        qb, CC, (long long)DD,
        qkv + CC, C3, (long long)DD,
        attn, (long long)(NN * NN), gpart, (long long)(NN * NN),
        NN, NN, DD / 24, 24);

    // 4. softmax (fuses split-K reduce, scale, +0.1*Pq)
    softmax_kernel<<<120, 256, 0, stream>>>(attn, gpart, 23, qmaxb);

    // 5. preb = bf16(attn @ V)
    pv_kernel<<<dim3(12, 15, HH), 256, 0, stream>>>(attn, qkv, preb);

    // 6. out = pre @ w_proj^T + b_proj (KS=4, 384 blocks, Kc=1536, nT=12)
    gemm_pc<<<dim3(CC / 64, 1, 4), 320, 0, stream>>>(
        preb, CC, w_proj, CC, b_proj,
        out, gpart, (long long)f_pre,
        CC, CC, CC / 4, 4, nullptr);
    reduce_proj<<<1440, 256, 0, stream>>>((float4*)out, (const float4*)gpart,
        (long long)(f_pre / 4));
}